// Round 10
// baseline (343.139 us; speedup 1.0000x reference)
//
#include <hip/hip_runtime.h>
#include <hip/hip_bf16.h>

// GraphSAGE on MI355X — round 25: feature-chunked XCD-partitioned gather.
// The aggs (~108us of ~190 controllable) were L2-capacity-bound: every XCD
// touched the whole 12.8MB table -> 4MiB L2 thrash -> L3 random-line BW.
// Fix: chunk-major feature layout (X16c/HaC/AGGc[4][NN][32], G2c[2][NN][32];
// 64B rows = 1 line) + chunk = (blockIdx&7)/XCDs-per-chunk so each XCD pair
// gathers from a 3.2MB slice that FITS its L2. Chunk order == GEMM K-block
// order (kb&3), so GEMM staging is a pure address change. Perf-safe: if the
// bid%8->XCD mapping assumption fails we fall back to today's L3 speed.
// Also: cvt moved p2->p1 (independent, balances prep dispatches).
// Dispatches: memset(4B), p1(+cvt+wprep), p2(binning), aggc0, gemm0,
//             aggc1, gemm1d7, aggaccc.

#define NFEAT 128
#define SLOTS 64
#define BSH 9
#define BNODES (1 << BSH)    // 512 nodes per bucket
#define MAXBK 100            // nbk = ceil(50000/512) = 98
#define LCAP 64              // per-block per-bucket segment entries (mean ~42)
#define LSH 6
#define MAXTB 256            // max edge blocks (tb = 196 for E=800K)

typedef __attribute__((ext_vector_type(8))) short short8;
typedef __attribute__((ext_vector_type(4))) float floatx4;

__device__ __forceinline__ float bf_lo(unsigned u) { return __uint_as_float(u << 16); }
__device__ __forceinline__ float bf_hi(unsigned u) { return __uint_as_float(u & 0xffff0000u); }
__device__ __forceinline__ ushort f2bf(float f) {
    __hip_bfloat16 h = __float2bfloat16(f);
    return *(ushort*)&h;
}
__device__ __forceinline__ unsigned pack2(float a, float b) {
    return (unsigned)f2bf(a) | ((unsigned)f2bf(b) << 16);
}

// ---------------- P1: edge bucket-scatter + x->bf16 chunked cvt + weight prep ----------------

__global__ __launch_bounds__(256) void k_p1(
    const int* __restrict__ dst, const int* __restrict__ src,
    unsigned* __restrict__ gbuf, int* __restrict__ lcnt_g,
    unsigned* __restrict__ spill, int* __restrict__ spill_cnt,
    int E, int nbk, int tb, int epb,
    const float* __restrict__ X, ushort* __restrict__ X16, int n2, int NN,
    const float* __restrict__ Ws0, const float* __restrict__ Wn0,
    const float* __restrict__ Ws1, const float* __restrict__ Wn1,
    const float* __restrict__ Ws2, const float* __restrict__ Wn2,
    ushort* __restrict__ Wt0, ushort* __restrict__ Wt1, ushort* __restrict__ Wt2,
    int cvtb) {
    int b = blockIdx.x, t = threadIdx.x;
    if (b < tb) {
        __shared__ unsigned lists[MAXBK * LCAP];
        __shared__ int lcnt[MAXBK];
        for (int i = t; i < MAXBK; i += 256) lcnt[i] = 0;
        __syncthreads();

        int tile0 = b * epb;
        for (int off = t * 4; off < epb; off += 1024) {
            int base = tile0 + off;
            if (base + 4 <= E) {
                int4 d4 = *(const int4*)(dst + base);
                int4 s4 = *(const int4*)(src + base);
                int dd[4] = {d4.x, d4.y, d4.z, d4.w};
                int ss[4] = {s4.x, s4.y, s4.z, s4.w};
#pragma unroll
                for (int j = 0; j < 4; ++j) {
                    int bkt = dd[j] >> BSH;
                    unsigned pk = ((unsigned)ss[j] << 16) | (unsigned)dd[j];
                    int pos = atomicAdd(&lcnt[bkt], 1);
                    if (pos < LCAP) {
                        lists[(bkt << LSH) + pos] = pk;
                    } else {
                        int g = atomicAdd(spill_cnt, 1);
                        spill[g] = pk;
                    }
                }
            } else {
                for (int e = base; e < E && e < base + 4; ++e) {
                    int d = dst[e];
                    int bkt = d >> BSH;
                    unsigned pk = ((unsigned)src[e] << 16) | (unsigned)d;
                    int pos = atomicAdd(&lcnt[bkt], 1);
                    if (pos < LCAP) {
                        lists[(bkt << LSH) + pos] = pk;
                    } else {
                        int g = atomicAdd(spill_cnt, 1);
                        spill[g] = pk;
                    }
                }
            }
        }
        __syncthreads();

        // deterministic flush: plain stores only, no atomics
        int lane = t & 63, wid = t >> 6;
        for (int bk = wid; bk < nbk; bk += 4) {
            int c = lcnt[bk];
            if (c > LCAP) c = LCAP;
            if (lane == 0) lcnt_g[bk * tb + b] = c;
            unsigned* seg = gbuf + (((size_t)bk * tb + b) << LSH);
            for (int i = lane; i < c; i += 64) seg[i] = lists[(bk << LSH) + i];
        }
    } else if (b < tb + cvtb) {
        // x -> bf16, chunk-major: X16c[c][n][32], c = chunk of 32 feats
        int i = (b - tb) * 256 + t;
        if (i < n2) {
            float2 v = ((const float2*)X)[i];
            int n = i >> 6, c = (i & 63) >> 4, f2 = i & 15;
            ((unsigned*)(X16 + ((size_t)c * NN + n) * 32))[f2] = pack2(v.x, v.y);
        }
    } else {
        int idx = (b - tb - cvtb) * 256 + t;
        if (idx < 32768) {
            int n = idx >> 8, k = idx & 255;
            Wt0[idx] = f2bf(k < 128 ? Ws0[k * 128 + n] : Wn0[(k - 128) * 128 + n]);
        } else if (idx < 65536) {
            int l = idx - 32768, n = l >> 8, k = l & 255;
            Wt1[l] = f2bf(k < 128 ? Ws1[k * 128 + n] : Wn1[(k - 128) * 128 + n]);
        } else if (idx < 81920) {
            int l = idx - 65536, n = l >> 8, k = l & 255;
            Wt2[l] = f2bf(k < 128 ? Ws2[k * 64 + n] : Wn2[(k - 128) * 64 + n]);
        }
    }
}

// ---------------- P2: per-bucket binning (LDS counters) ----------------

__global__ __launch_bounds__(256) void k_p2(
    const unsigned* __restrict__ gbuf, const int* __restrict__ lcnt_g,
    const unsigned* __restrict__ spill, const int* __restrict__ spill_cnt,
    int* __restrict__ deg, ushort* __restrict__ csr, int NN, int nbk, int tb) {
    int b = blockIdx.x, t = threadIdx.x;
    __shared__ int cnt[BNODES];
    __shared__ int scnt[MAXTB];
    for (int i = t; i < BNODES; i += 256) cnt[i] = 0;
    for (int i = t; i < tb; i += 256) scnt[i] = lcnt_g[b * tb + i];
    __syncthreads();
    int n0 = b << BSH;
    const unsigned* bp = gbuf + (((size_t)b * tb) << LSH);
    int total = tb << LSH;
    for (int j0 = t * 4; j0 < total; j0 += 1024) {
        int blk = j0 >> LSH;
        int c = scnt[blk];
        int idx0 = j0 & (LCAP - 1);
        uint4 v = *(const uint4*)(bp + j0);
        unsigned pp[4] = {v.x, v.y, v.z, v.w};
#pragma unroll
        for (int k = 0; k < 4; ++k) {
            if (idx0 + k < c) {
                unsigned p = pp[k];
                int d = (int)(p & 0xFFFFu);
                int s = (int)(p >> 16);
                int r = atomicAdd(&cnt[d - n0], 1);
                if (r < SLOTS) csr[(d << 6) + r] = (ushort)s;
            }
        }
    }
    int ns = *spill_cnt;
    for (int j = t; j < ns; j += 256) {
        unsigned p = spill[j];
        int d = (int)(p & 0xFFFFu);
        if ((d >> BSH) == b) {
            int s = (int)(p >> 16);
            int r = atomicAdd(&cnt[d - n0], 1);
            if (r < SLOTS) csr[(d << 6) + r] = (ushort)s;
        }
    }
    __syncthreads();
    for (int i = t; i < BNODES; i += 256) {
        int n = n0 + i;
        if (n < NN) deg[n] = cnt[i];
    }
}

// ---------------- chunked mean aggregation ----------------
// H is chunk-major [NCH][NN][32]. Block's chunk = (bid&7)/XPC so each XCD
// group gathers from a 3.2MB slice (L2-resident). Wave: 16 slots x 4 lanes
// x 16B -> 1KB/load-instr; 4 rounds cover all 64 slots (no tail).
// MODE 0: write bf16 chunk-major table; MODE 2: out[n*64+chunk*32+..] += fp32.

template <int NCH, int MODE>
__device__ __forceinline__ void aggc_body(int bid, int nb, int t,
    const ushort* __restrict__ H, const int* __restrict__ deg,
    const ushort* __restrict__ csr, void* __restrict__ outp, int NN) {
    constexpr int XPC = 8 / NCH;
    int lane = t & 63, wid = t >> 6;
    int sub = lane >> 2, fl = lane & 3;
    int x = bid & 7, g = bid >> 3;
    int chunk = x / XPC, sb = x % XPC;
    int NB = (nb >> 3) * XPC;
    int node = (g * XPC + sb) * 4 + wid;
    int wstr = NB * 4;
    const ushort* Hc = H + (size_t)chunk * NN * 32;

    int d_cur = 0;
    int s_cur[4];
    if (node < NN) {
        d_cur = deg[node];
        const ushort* sl = csr + (node << 6);
#pragma unroll
        for (int k = 0; k < 4; ++k) s_cur[k] = sl[k * 16 + sub];
    }

    while (node < NN) {
        int nnode = node + wstr;
        int d_nxt = 0;
        int s_nxt[4];
        if (nnode < NN) {
            d_nxt = deg[nnode];
            const ushort* sl = csr + (nnode << 6);
#pragma unroll
            for (int k = 0; k < 4; ++k) s_nxt[k] = sl[k * 16 + sub];
        }

        int dd = d_cur;
        int d = (dd < SLOTS) ? dd : SLOTS;
        float acc[8] = {};
        uint4 v[4];
#pragma unroll
        for (int k = 0; k < 4; ++k) {
            v[k] = make_uint4(0, 0, 0, 0);
            if (k * 16 + sub < d)
                v[k] = *(const uint4*)(Hc + (size_t)s_cur[k] * 32 + fl * 8);
        }
#pragma unroll
        for (int k = 0; k < 4; ++k) {
            acc[0] += bf_lo(v[k].x); acc[1] += bf_hi(v[k].x);
            acc[2] += bf_lo(v[k].y); acc[3] += bf_hi(v[k].y);
            acc[4] += bf_lo(v[k].z); acc[5] += bf_hi(v[k].z);
            acc[6] += bf_lo(v[k].w); acc[7] += bf_hi(v[k].w);
        }
#pragma unroll
        for (int off = 4; off < 64; off <<= 1)
#pragma unroll
            for (int i = 0; i < 8; ++i) acc[i] += __shfl_xor(acc[i], off, 64);
        if (sub == 0) {
            float inv = (dd > 0) ? 1.0f / (float)dd : 0.0f;
            if constexpr (MODE == 0) {
                unsigned u[4];
#pragma unroll
                for (int i = 0; i < 4; ++i)
                    u[i] = pack2(acc[2 * i] * inv, acc[2 * i + 1] * inv);
                *(uint4*)((ushort*)outp + ((size_t)chunk * NN + node) * 32 + fl * 8) =
                    make_uint4(u[0], u[1], u[2], u[3]);
            } else {
                float* O = (float*)outp;
                size_t base = (size_t)node * 64 + chunk * 32 + fl * 8;
#pragma unroll
                for (int i = 0; i < 8; ++i) O[base + i] += acc[i] * inv;
            }
        }
        node = nnode;
        d_cur = d_nxt;
#pragma unroll
        for (int k = 0; k < 4; ++k) s_cur[k] = s_nxt[k];
    }
}

__global__ __launch_bounds__(256) void k_aggc128(
    const ushort* __restrict__ H, const int* __restrict__ deg,
    const ushort* __restrict__ csr, void* __restrict__ outp, int NN) {
    aggc_body<4, 0>(blockIdx.x, gridDim.x, threadIdx.x, H, deg, csr, outp, NN);
}

__global__ __launch_bounds__(256) void k_aggaccc(
    const ushort* __restrict__ G2, const int* __restrict__ deg,
    const ushort* __restrict__ csr, float* __restrict__ out, int NN) {
    aggc_body<2, 2>(blockIdx.x, gridDim.x, threadIdx.x, G2, deg, csr, out, NN);
}

// ---------------- MFMA GEMM (chunk-major A) ----------------
// C = [Hs | Ag] @ Wt^T + bias, ReLU. Hs/Ag chunk-major [4][NN][32]; kb&3 is
// the chunk. FUSE_D7: Hb tile -> LDS -> out_self (fp32) + G2 (bf16 chunked).

template <bool FUSE_D7>
__device__ __forceinline__ void gemm_body(int bid, int t,
    const ushort* __restrict__ Hs, const ushort* __restrict__ Ag,
    const ushort* __restrict__ Wt, const float* __restrict__ bias,
    ushort* __restrict__ HoutC, int M, int NN,
    const ushort* __restrict__ Wt2, const float* __restrict__ b2,
    ushort* __restrict__ G2, float* __restrict__ outF) {
    constexpr int LDA = 40;
    __shared__ ushort Asl[64 * LDA];
    __shared__ ushort Bsl[128 * LDA];

    int lane = t & 63;
    int wid = t >> 6;
    int wm = wid & 1, wn = wid >> 1;
    int l15 = lane & 15, quad = lane >> 4;
    int m0 = bid * 64;

    floatx4 acc[2][4] = {};

    for (int kb = 0; kb < 8; ++kb) {
        const ushort* Asrc = (kb < 4) ? Hs : Ag;
        const ushort* Ac = Asrc + (size_t)(kb & 3) * NN * 32;
        __syncthreads();
#pragma unroll
        for (int id = t; id < 64 * 4; id += 256) {
            int r = id >> 2, p = id & 3;
            uint4 v = make_uint4(0, 0, 0, 0);
            if (m0 + r < M) v = *(const uint4*)(Ac + (size_t)(m0 + r) * 32 + p * 8);
            *(uint4*)(&Asl[r * LDA + p * 8]) = v;
        }
#pragma unroll
        for (int id = t; id < 128 * 4; id += 256) {
            int r = id >> 2, p = id & 3;
            uint4 v = *(const uint4*)(Wt + (size_t)r * 256 + kb * 32 + p * 8);
            *(uint4*)(&Bsl[r * LDA + p * 8]) = v;
        }
        __syncthreads();

        short8 a[2], b[4];
#pragma unroll
        for (int mt = 0; mt < 2; ++mt)
            a[mt] = *(const short8*)(&Asl[(wm * 32 + mt * 16 + l15) * LDA + quad * 8]);
#pragma unroll
        for (int nt = 0; nt < 4; ++nt)
            b[nt] = *(const short8*)(&Bsl[(wn * 64 + nt * 16 + l15) * LDA + quad * 8]);
#pragma unroll
        for (int mt = 0; mt < 2; ++mt)
#pragma unroll
            for (int nt = 0; nt < 4; ++nt)
                acc[mt][nt] = __builtin_amdgcn_mfma_f32_16x16x32_bf16(a[mt], b[nt], acc[mt][nt], 0, 0, 0);
    }

    if constexpr (!FUSE_D7) {
        // epilogue: ReLU + bf16 chunk-major store
#pragma unroll
        for (int mt = 0; mt < 2; ++mt) {
            int mbase = m0 + wm * 32 + mt * 16 + quad * 4;
#pragma unroll
            for (int nt = 0; nt < 4; ++nt) {
                int col = wn * 64 + nt * 16 + l15;
                float bv = bias[col];
                ushort* dst = HoutC + (size_t)(col >> 5) * NN * 32 + (col & 31);
#pragma unroll
                for (int r = 0; r < 4; ++r) {
                    int m = mbase + r;
                    if (m < M) {
                        float v = acc[mt][nt][r] + bv;
                        v = fmaxf(v, 0.f);
                        dst[(size_t)m * 32] = f2bf(v);
                    }
                }
            }
        }
    } else {
        constexpr int LDG = 136;
        __shared__ ushort Hbl[64 * LDG];
#pragma unroll
        for (int mt = 0; mt < 2; ++mt) {
            int rbase = wm * 32 + mt * 16 + quad * 4;
#pragma unroll
            for (int nt = 0; nt < 4; ++nt) {
                int col = wn * 64 + nt * 16 + l15;
                float bv = bias[col];
#pragma unroll
                for (int r = 0; r < 4; ++r) {
                    float v = acc[mt][nt][r] + bv;
                    v = fmaxf(v, 0.f);
                    Hbl[(rbase + r) * LDG + col] = f2bf(v);
                }
            }
        }

        floatx4 accS[4] = {};
        floatx4 accP[4] = {};
#pragma unroll
        for (int half = 0; half < 2; ++half) {
#pragma unroll
            for (int kb = 0; kb < 4; ++kb) {
                __syncthreads();
#pragma unroll
                for (int id = t; id < 64 * 4; id += 256) {
                    int r = id >> 2, p = id & 3;
                    uint4 v = *(const uint4*)(Wt2 + (size_t)r * 256 + half * 128 + kb * 32 + p * 8);
                    *(uint4*)(&Bsl[r * LDA + p * 8]) = v;
                }
                __syncthreads();
                short8 a = *(const short8*)(&Hbl[(wid * 16 + l15) * LDG + kb * 32 + quad * 8]);
#pragma unroll
                for (int nt = 0; nt < 4; ++nt) {
                    short8 b = *(const short8*)(&Bsl[(nt * 16 + l15) * LDA + quad * 8]);
                    if (half == 0)
                        accS[nt] = __builtin_amdgcn_mfma_f32_16x16x32_bf16(a, b, accS[nt], 0, 0, 0);
                    else
                        accP[nt] = __builtin_amdgcn_mfma_f32_16x16x32_bf16(a, b, accP[nt], 0, 0, 0);
                }
            }
        }
#pragma unroll
        for (int nt = 0; nt < 4; ++nt) {
            int col = nt * 16 + l15;
            float bv = b2[col];
            ushort* g2d = G2 + (size_t)(col >> 5) * NN * 32 + (col & 31);
#pragma unroll
            for (int r = 0; r < 4; ++r) {
                int m = m0 + wid * 16 + quad * 4 + r;
                if (m < M) {
                    outF[(size_t)m * 64 + col] = accS[nt][r] + bv;
                    g2d[(size_t)m * 32] = f2bf(accP[nt][r]);
                }
            }
        }
    }
}

__global__ __launch_bounds__(256) void k_gemm0(
    const ushort* __restrict__ Hs, const ushort* __restrict__ Ag,
    const ushort* __restrict__ Wt, const float* __restrict__ bias,
    ushort* __restrict__ HoutC, int M, int NN) {
    gemm_body<false>(blockIdx.x, threadIdx.x, Hs, Ag, Wt, bias, HoutC, M, NN,
                     nullptr, nullptr, nullptr, nullptr);
}

__global__ __launch_bounds__(256) void k_gemm1d7(
    const ushort* __restrict__ Hs, const ushort* __restrict__ Ag,
    const ushort* __restrict__ Wt, const float* __restrict__ bias,
    const ushort* __restrict__ Wt2, const float* __restrict__ b2,
    ushort* __restrict__ G2, float* __restrict__ out, int M, int NN) {
    gemm_body<true>(blockIdx.x, threadIdx.x, Hs, Ag, Wt, bias, nullptr, M, NN,
                    Wt2, b2, G2, out);
}

// ---------------- launch ----------------

static inline size_t align_up(size_t x) { return (x + 255) & ~(size_t)255; }

extern "C" void kernel_launch(void* const* d_in, const int* in_sizes, int n_in,
                              void* d_out, int out_size, void* d_ws, size_t ws_size,
                              hipStream_t stream) {
    const float* x   = (const float*)d_in[0];
    const int*   src = (const int*)d_in[1];
    const int*   dst = (const int*)d_in[2];
    const float* Ws0 = (const float*)d_in[3];
    const float* Wn0 = (const float*)d_in[4];
    const float* b0  = (const float*)d_in[5];
    const float* Ws1 = (const float*)d_in[6];
    const float* Wn1 = (const float*)d_in[7];
    const float* b1  = (const float*)d_in[8];
    const float* Ws2 = (const float*)d_in[9];
    const float* Wn2 = (const float*)d_in[10];
    const float* b2  = (const float*)d_in[11];
    float* out = (float*)d_out;

    const int NN = in_sizes[0] / NFEAT;   // 50000
    const int E  = in_sizes[1];           // 800000

    char* w = (char*)d_ws;
    ushort* X16  = (ushort*)w; w += align_up((size_t)NN * NFEAT * 2);   // chunk-major [4][NN][32]
    ushort* Ha   = (ushort*)w; w += align_up((size_t)NN * NFEAT * 2);   // chunk-major [4][NN][32]
    ushort* Hb   = (ushort*)w; w += align_up((size_t)NN * NFEAT * 2);   // scratch only
    ushort* AGG  = (ushort*)w; w += align_up((size_t)NN * NFEAT * 2);   // chunk-major [4][NN][32]
    ushort* Wt0  = (ushort*)w; w += align_up((size_t)128 * 256 * 2);
    ushort* Wt1  = (ushort*)w; w += align_up((size_t)128 * 256 * 2);
    ushort* Wt2  = (ushort*)w; w += align_up((size_t)64 * 256 * 2);
    int* deg     = (int*)w;    w += align_up((size_t)NN * 4);
    ushort* csr  = (ushort*)w; w += align_up((size_t)NN * SLOTS * 2);   // 6.4 MB slot bins

    // edge-block geometry (tb=196 for E=800K)
    int epb = 4096;
    int tb = (E + epb - 1) / epb;
    if (tb > MAXTB) { epb = ((E + MAXTB - 1) / MAXTB + 1023) & ~(size_t)1023; tb = (E + epb - 1) / epb; }
    const int nbk = (NN + BNODES - 1) >> BSH;                           // 98

    // aliased scratch (lifetimes disjoint — all consumed by P2; later writers run after):
    unsigned* gbuf   = (unsigned*)Ha;     // nbk*tb*64*4 = 4.9 MB (Ha written by gemm0, after P2)
    int* lcnt_g      = (int*)Hb;          // nbk*tb*4 = 77 KB
    int* spill_cnt   = lcnt_g + nbk * tb; // 4 B
    unsigned* spill  = (unsigned*)AGG;    // up to E*4 = 3.2 MB (AGG written by aggc0, after P2)
    ushort* G2       = X16;               // chunk-major [2][NN][32] (X16 dead after gemm0)

    hipMemsetAsync(spill_cnt, 0, 4, stream);

    const int n2   = NN * NFEAT / 2;
    const int cvtb = (n2 + 255) / 256;        // 782
    const int wb   = (81920 + 255) / 256;     // 320
    const int gm   = (NN + 63) / 64;          // 782 (BM=64)
    const int agb  = 2048;                    // multiple of 8 (XCD chunk mapping)

    // P1: bucket-scatter + chunked cvt + weight prep
    k_p1<<<tb + cvtb + wb, 256, 0, stream>>>(
        dst, src, gbuf, lcnt_g, spill, spill_cnt, E, nbk, tb, epb,
        x, X16, n2, NN,
        Ws0, Wn0, Ws1, Wn1, Ws2, Wn2, Wt0, Wt1, Wt2, cvtb);

    // P2: per-bucket binning (LDS atomics)
    k_p2<<<nbk, 256, 0, stream>>>(
        gbuf, lcnt_g, spill, spill_cnt, deg, csr, NN, nbk, tb);

    // layer 0: chunked agg(X16) -> AGG; gemm -> Ha (chunk-major, ReLU)
    k_aggc128<<<agb, 256, 0, stream>>>(X16, deg, csr, AGG, NN);
    k_gemm0<<<gm, 256, 0, stream>>>(X16, AGG, Wt0, b0, Ha, NN, NN);

    // layer 1 + d7: chunked agg(Ha) -> AGG; gemm1d7 -> out_self + G2 (chunked)
    k_aggc128<<<agb, 256, 0, stream>>>(Ha, deg, csr, AGG, NN);
    k_gemm1d7<<<gm, 256, 0, stream>>>(Ha, AGG, Wt1, b1, Wt2, b2, G2, out, NN, NN);

    // final: out += mean-gather(G2) (2 chunks)
    k_aggaccc<<<agb, 256, 0, stream>>>(G2, deg, csr, out, NN);
}

// Round 11
// 232.330 us; speedup vs baseline: 1.4769x; 1.4769x over previous
//
#include <hip/hip_runtime.h>
#include <hip/hip_bf16.h>

// GraphSAGE on MI355X — round 26: revert round-25's chunked gather (VALU-bound
// regression: 4x per-node overhead, VALUBusy 52%; FETCH=31MB proved caches
// already absorb the gather — memory was not the limiter). Back to the r24
// anchor (233.8us) with one kept change: fp32->bf16 cvt moved p2 -> p1
// (row-major pack; p2 becomes pure binning ~8-10us; p1 has idle CUs).
// Dispatches: memset(4B), p1(scatter+cvt+wprep), p2(binning), agg0, gemm0,
//             agg1, gemm1d7, aggacc.

#define NFEAT 128
#define SLOTS 64
#define BSH 9
#define BNODES (1 << BSH)    // 512 nodes per bucket
#define MAXBK 100            // nbk = ceil(50000/512) = 98
#define LCAP 64              // per-block per-bucket segment entries (mean ~42)
#define LSH 6
#define MAXTB 256            // max edge blocks (tb = 196 for E=800K)

typedef __attribute__((ext_vector_type(8))) short short8;
typedef __attribute__((ext_vector_type(4))) float floatx4;

__device__ __forceinline__ float bf_lo(unsigned u) { return __uint_as_float(u << 16); }
__device__ __forceinline__ float bf_hi(unsigned u) { return __uint_as_float(u & 0xffff0000u); }
__device__ __forceinline__ ushort f2bf(float f) {
    __hip_bfloat16 h = __float2bfloat16(f);
    return *(ushort*)&h;
}
__device__ __forceinline__ unsigned pack2(float a, float b) {
    return (unsigned)f2bf(a) | ((unsigned)f2bf(b) << 16);
}

// ---------------- P1: edge bucket-scatter + x->bf16 cvt + weight prep ----------------

__global__ __launch_bounds__(256) void k_p1(
    const int* __restrict__ dst, const int* __restrict__ src,
    unsigned* __restrict__ gbuf, int* __restrict__ lcnt_g,
    unsigned* __restrict__ spill, int* __restrict__ spill_cnt,
    int E, int nbk, int tb, int epb,
    const float* __restrict__ X, ushort* __restrict__ X16, int n2,
    const float* __restrict__ Ws0, const float* __restrict__ Wn0,
    const float* __restrict__ Ws1, const float* __restrict__ Wn1,
    const float* __restrict__ Ws2, const float* __restrict__ Wn2,
    ushort* __restrict__ Wt0, ushort* __restrict__ Wt1, ushort* __restrict__ Wt2,
    int cvtb) {
    int b = blockIdx.x, t = threadIdx.x;
    if (b < tb) {
        __shared__ unsigned lists[MAXBK * LCAP];
        __shared__ int lcnt[MAXBK];
        for (int i = t; i < MAXBK; i += 256) lcnt[i] = 0;
        __syncthreads();

        int tile0 = b * epb;
        for (int off = t * 4; off < epb; off += 1024) {
            int base = tile0 + off;
            if (base + 4 <= E) {
                int4 d4 = *(const int4*)(dst + base);
                int4 s4 = *(const int4*)(src + base);
                int dd[4] = {d4.x, d4.y, d4.z, d4.w};
                int ss[4] = {s4.x, s4.y, s4.z, s4.w};
#pragma unroll
                for (int j = 0; j < 4; ++j) {
                    int bkt = dd[j] >> BSH;
                    unsigned pk = ((unsigned)ss[j] << 16) | (unsigned)dd[j];
                    int pos = atomicAdd(&lcnt[bkt], 1);
                    if (pos < LCAP) {
                        lists[(bkt << LSH) + pos] = pk;
                    } else {
                        int g = atomicAdd(spill_cnt, 1);
                        spill[g] = pk;
                    }
                }
            } else {
                for (int e = base; e < E && e < base + 4; ++e) {
                    int d = dst[e];
                    int bkt = d >> BSH;
                    unsigned pk = ((unsigned)src[e] << 16) | (unsigned)d;
                    int pos = atomicAdd(&lcnt[bkt], 1);
                    if (pos < LCAP) {
                        lists[(bkt << LSH) + pos] = pk;
                    } else {
                        int g = atomicAdd(spill_cnt, 1);
                        spill[g] = pk;
                    }
                }
            }
        }
        __syncthreads();

        // deterministic flush: plain stores only, no atomics
        int lane = t & 63, wid = t >> 6;
        for (int bk = wid; bk < nbk; bk += 4) {
            int c = lcnt[bk];
            if (c > LCAP) c = LCAP;
            if (lane == 0) lcnt_g[bk * tb + b] = c;
            unsigned* seg = gbuf + (((size_t)bk * tb + b) << LSH);
            for (int i = lane; i < c; i += 64) seg[i] = lists[(bk << LSH) + i];
        }
    } else if (b < tb + cvtb) {
        int i = (b - tb) * 256 + t;
        if (i < n2) {
            float2 v = ((const float2*)X)[i];
            ((unsigned*)X16)[i] = pack2(v.x, v.y);
        }
    } else {
        int idx = (b - tb - cvtb) * 256 + t;
        if (idx < 32768) {
            int n = idx >> 8, k = idx & 255;
            Wt0[idx] = f2bf(k < 128 ? Ws0[k * 128 + n] : Wn0[(k - 128) * 128 + n]);
        } else if (idx < 65536) {
            int l = idx - 32768, n = l >> 8, k = l & 255;
            Wt1[l] = f2bf(k < 128 ? Ws1[k * 128 + n] : Wn1[(k - 128) * 128 + n]);
        } else if (idx < 81920) {
            int l = idx - 65536, n = l >> 8, k = l & 255;
            Wt2[l] = f2bf(k < 128 ? Ws2[k * 64 + n] : Wn2[(k - 128) * 64 + n]);
        }
    }
}

// ---------------- P2: per-bucket binning (LDS counters) ----------------

__global__ __launch_bounds__(256) void k_p2(
    const unsigned* __restrict__ gbuf, const int* __restrict__ lcnt_g,
    const unsigned* __restrict__ spill, const int* __restrict__ spill_cnt,
    int* __restrict__ deg, ushort* __restrict__ csr, int NN, int nbk, int tb) {
    int b = blockIdx.x, t = threadIdx.x;
    __shared__ int cnt[BNODES];
    __shared__ int scnt[MAXTB];
    for (int i = t; i < BNODES; i += 256) cnt[i] = 0;
    for (int i = t; i < tb; i += 256) scnt[i] = lcnt_g[b * tb + i];
    __syncthreads();
    int n0 = b << BSH;
    const unsigned* bp = gbuf + (((size_t)b * tb) << LSH);
    int total = tb << LSH;
    // 4 slots/thread, unconditional uint4 load; predicate the use only.
    for (int j0 = t * 4; j0 < total; j0 += 1024) {
        int blk = j0 >> LSH;
        int c = scnt[blk];
        int idx0 = j0 & (LCAP - 1);
        uint4 v = *(const uint4*)(bp + j0);
        unsigned pp[4] = {v.x, v.y, v.z, v.w};
#pragma unroll
        for (int k = 0; k < 4; ++k) {
            if (idx0 + k < c) {
                unsigned p = pp[k];
                int d = (int)(p & 0xFFFFu);
                int s = (int)(p >> 16);
                int r = atomicAdd(&cnt[d - n0], 1);
                if (r < SLOTS) csr[(d << 6) + r] = (ushort)s;
            }
        }
    }
    // rare overflow spill (expected ~handful of entries)
    int ns = *spill_cnt;
    for (int j = t; j < ns; j += 256) {
        unsigned p = spill[j];
        int d = (int)(p & 0xFFFFu);
        if ((d >> BSH) == b) {
            int s = (int)(p >> 16);
            int r = atomicAdd(&cnt[d - n0], 1);
            if (r < SLOTS) csr[(d << 6) + r] = (ushort)s;
        }
    }
    __syncthreads();
    for (int i = t; i < BNODES; i += 256) {
        int n = n0 + i;
        if (n < NN) deg[n] = cnt[i];
    }
}

// ---------------- mean aggregation: persistent waves, cross-node pipelined ----------------
// MODE 0: write bf16; MODE 2: out += fp32.

template <int FEAT, int MODE>
__device__ __forceinline__ void agg_body(int vbid, int nb, int t,
    const ushort* __restrict__ H, const int* __restrict__ deg,
    const ushort* __restrict__ csr, void* __restrict__ outp, int NN) {
    constexpr int LPR = FEAT / 8;
    constexpr int EPG = 64 / LPR;
    constexpr int NS = 8;
    int lane = t & 63, wid = t >> 6;
    int sub = lane / LPR, fl = lane % LPR;
    int wstr = nb * 4;
    int node = vbid * 4 + wid;

    int d_cur = 0;
    int s_cur[NS];
    if (node < NN) {
        d_cur = deg[node];
        const ushort* slot = csr + (node << 6);
#pragma unroll
        for (int k = 0; k < NS; ++k) s_cur[k] = slot[k * EPG + sub];
    }

    while (node < NN) {
        int nnode = node + wstr;
        int d_nxt = 0;
        int s_nxt[NS];
        if (nnode < NN) {
            d_nxt = deg[nnode];
            const ushort* slot2 = csr + (nnode << 6);
#pragma unroll
            for (int k = 0; k < NS; ++k) s_nxt[k] = slot2[k * EPG + sub];
        }

        int dd = d_cur;
        int d = (dd < SLOTS) ? dd : SLOTS;
        float acc[8] = {};
        uint4 v[NS];
#pragma unroll
        for (int k = 0; k < NS; ++k) {
            int e = k * EPG + sub;
            v[k] = make_uint4(0, 0, 0, 0);
            if (e < d) v[k] = *(const uint4*)(H + (size_t)s_cur[k] * FEAT + fl * 8);
        }
#pragma unroll
        for (int k = 0; k < NS; ++k) {
            acc[0] += bf_lo(v[k].x); acc[1] += bf_hi(v[k].x);
            acc[2] += bf_lo(v[k].y); acc[3] += bf_hi(v[k].y);
            acc[4] += bf_lo(v[k].z); acc[5] += bf_hi(v[k].z);
            acc[6] += bf_lo(v[k].w); acc[7] += bf_hi(v[k].w);
        }
        if constexpr (NS * EPG < SLOTS) {
            if (d > NS * EPG) {
                const ushort* slot = csr + (node << 6);
                for (int e = NS * EPG + sub; e < d; e += EPG) {
                    int r = slot[e];
                    uint4 vv = *(const uint4*)(H + (size_t)r * FEAT + fl * 8);
                    acc[0] += bf_lo(vv.x); acc[1] += bf_hi(vv.x);
                    acc[2] += bf_lo(vv.y); acc[3] += bf_hi(vv.y);
                    acc[4] += bf_lo(vv.z); acc[5] += bf_hi(vv.z);
                    acc[6] += bf_lo(vv.w); acc[7] += bf_hi(vv.w);
                }
            }
        }
#pragma unroll
        for (int off = LPR; off < 64; off <<= 1)
#pragma unroll
            for (int i = 0; i < 8; ++i) acc[i] += __shfl_xor(acc[i], off, 64);
        if (sub == 0) {
            float inv = (dd > 0) ? 1.0f / (float)dd : 0.0f;
            if constexpr (MODE == 0) {
                unsigned u[4];
#pragma unroll
                for (int i = 0; i < 4; ++i)
                    u[i] = pack2(acc[2 * i] * inv, acc[2 * i + 1] * inv);
                *(uint4*)((ushort*)outp + (size_t)node * FEAT + fl * 8) =
                    make_uint4(u[0], u[1], u[2], u[3]);
            } else {
                float* O = (float*)outp;
                size_t b = (size_t)node * FEAT + fl * 8;
#pragma unroll
                for (int i = 0; i < 8; ++i) O[b + i] += acc[i] * inv;
            }
        }
        node = nnode;
        d_cur = d_nxt;
#pragma unroll
        for (int k = 0; k < NS; ++k) s_cur[k] = s_nxt[k];
    }
}

__global__ __launch_bounds__(256) void k_agg128(
    const ushort* __restrict__ H, const int* __restrict__ deg,
    const ushort* __restrict__ csr, void* __restrict__ outp, int NN) {
    agg_body<128, 0>(blockIdx.x, gridDim.x, threadIdx.x, H, deg, csr, outp, NN);
}

__global__ __launch_bounds__(256) void k_aggacc(
    const ushort* __restrict__ G2, const int* __restrict__ deg,
    const ushort* __restrict__ csr, float* __restrict__ out, int NN) {
    agg_body<64, 2>(blockIdx.x, gridDim.x, threadIdx.x, G2, deg, csr, out, NN);
}

// ---------------- MFMA GEMM ----------------
// C = [Hs | Ag] @ Wt^T + bias (+ReLU). LDS rows padded to 40 ushorts.
// FUSE_D7 (r23/r24-verified epilogue): Hb tile -> LDS (ReLU,bf16) -> two
// K=128 mini-GEMMs -> out (fp32, +b2) and G2 (bf16). No Hb global traffic.

template <int BM, int BN, int NKB, bool SPLIT, bool OUT_BF16, bool FUSE_D7>
__device__ __forceinline__ void gemm_body(int bid, int t,
    const ushort* __restrict__ Hs, const ushort* __restrict__ Ag,
    const ushort* __restrict__ Wt, int ldw, const float* __restrict__ bias,
    void* __restrict__ Cout, int M, int relu,
    const ushort* __restrict__ Wt2, const float* __restrict__ b2,
    ushort* __restrict__ G2, float* __restrict__ outF) {
    constexpr int NW = BN / 64;
    constexpr int NTHR = 2 * NW * 64;
    constexpr int MT = BM / 32;
    constexpr int LDA = 40;
    __shared__ ushort Asl[BM * LDA];
    __shared__ ushort Bsl[BN * LDA];

    int lane = t & 63;
    int wid = t >> 6;
    int wm = wid & 1, wn = wid >> 1;
    int l15 = lane & 15, quad = lane >> 4;
    int m0 = bid * BM;

    floatx4 acc[MT][4] = {};

    for (int kb = 0; kb < NKB; ++kb) {
        const ushort* Asrc;
        int kOff;
        if constexpr (SPLIT) {
            Asrc = (kb < NKB / 2) ? Hs : Ag;
            kOff = (kb & (NKB / 2 - 1)) * 32;
        } else {
            Asrc = Hs;
            kOff = kb * 32;
        }
        __syncthreads();
#pragma unroll
        for (int id = t; id < BM * 4; id += NTHR) {
            int r = id >> 2, p = id & 3;
            uint4 v = make_uint4(0, 0, 0, 0);
            if (m0 + r < M) v = *(const uint4*)(Asrc + (size_t)(m0 + r) * NFEAT + kOff + p * 8);
            *(uint4*)(&Asl[r * LDA + p * 8]) = v;
        }
#pragma unroll
        for (int id = t; id < BN * 4; id += NTHR) {
            int r = id >> 2, p = id & 3;
            uint4 v = *(const uint4*)(Wt + (size_t)r * ldw + kb * 32 + p * 8);
            *(uint4*)(&Bsl[r * LDA + p * 8]) = v;
        }
        __syncthreads();

        short8 a[MT], b[4];
#pragma unroll
        for (int mt = 0; mt < MT; ++mt)
            a[mt] = *(const short8*)(&Asl[(wm * (MT * 16) + mt * 16 + l15) * LDA + quad * 8]);
#pragma unroll
        for (int nt = 0; nt < 4; ++nt)
            b[nt] = *(const short8*)(&Bsl[(wn * 64 + nt * 16 + l15) * LDA + quad * 8]);
#pragma unroll
        for (int mt = 0; mt < MT; ++mt)
#pragma unroll
            for (int nt = 0; nt < 4; ++nt)
                acc[mt][nt] = __builtin_amdgcn_mfma_f32_16x16x32_bf16(a[mt], b[nt], acc[mt][nt], 0, 0, 0);
    }

    if constexpr (!FUSE_D7) {
#pragma unroll
        for (int mt = 0; mt < MT; ++mt) {
            int mbase = m0 + wm * (MT * 16) + mt * 16 + quad * 4;
#pragma unroll
            for (int nt = 0; nt < 4; ++nt) {
                int col = wn * 64 + nt * 16 + l15;
                float bv = bias ? bias[col] : 0.0f;
#pragma unroll
                for (int r = 0; r < 4; ++r) {
                    int m = mbase + r;
                    if (m < M) {
                        float v = acc[mt][nt][r] + bv;
                        if (relu) v = fmaxf(v, 0.f);
                        if constexpr (OUT_BF16) {
                            ((unsigned short*)Cout)[(size_t)m * BN + col] = f2bf(v);
                        } else {
                            ((float*)Cout)[(size_t)m * BN + col] = v;
                        }
                    }
                }
            }
        }
    } else {
        constexpr int LDG = 136;
        __shared__ ushort Hbl[64 * LDG];
        // write Hb tile (ReLU, bf16) to LDS; main-loop LDS reads are done
        // for this thread; the loop's first barrier orders Hbl reads.
#pragma unroll
        for (int mt = 0; mt < MT; ++mt) {
            int rbase = wm * (MT * 16) + mt * 16 + quad * 4;
#pragma unroll
            for (int nt = 0; nt < 4; ++nt) {
                int col = wn * 64 + nt * 16 + l15;
                float bv = bias[col];
#pragma unroll
                for (int r = 0; r < 4; ++r) {
                    float v = acc[mt][nt][r] + bv;
                    v = fmaxf(v, 0.f);
                    Hbl[(rbase + r) * LDG + col] = f2bf(v);
                }
            }
        }

        floatx4 accS[4] = {};
        floatx4 accP[4] = {};
#pragma unroll
        for (int half = 0; half < 2; ++half) {
#pragma unroll
            for (int kb = 0; kb < 4; ++kb) {
                __syncthreads();
#pragma unroll
                for (int id = t; id < 64 * 4; id += NTHR) {
                    int r = id >> 2, p = id & 3;
                    uint4 v = *(const uint4*)(Wt2 + (size_t)r * 256 + half * 128 + kb * 32 + p * 8);
                    *(uint4*)(&Bsl[r * LDA + p * 8]) = v;
                }
                __syncthreads();
                short8 a = *(const short8*)(&Hbl[(wid * 16 + l15) * LDG + kb * 32 + quad * 8]);
#pragma unroll
                for (int nt = 0; nt < 4; ++nt) {
                    short8 b = *(const short8*)(&Bsl[(nt * 16 + l15) * LDA + quad * 8]);
                    if (half == 0)
                        accS[nt] = __builtin_amdgcn_mfma_f32_16x16x32_bf16(a, b, accS[nt], 0, 0, 0);
                    else
                        accP[nt] = __builtin_amdgcn_mfma_f32_16x16x32_bf16(a, b, accP[nt], 0, 0, 0);
                }
            }
        }
#pragma unroll
        for (int nt = 0; nt < 4; ++nt) {
            int col = nt * 16 + l15;
            float bv = b2[col];
#pragma unroll
            for (int r = 0; r < 4; ++r) {
                int m = m0 + wid * 16 + quad * 4 + r;
                if (m < M) {
                    outF[(size_t)m * 64 + col] = accS[nt][r] + bv;
                    G2[(size_t)m * 64 + col] = f2bf(accP[nt][r]);
                }
            }
        }
    }
}

// L0: fused K=256 GEMM, bf16 out, ReLU -> Ha
__global__ __launch_bounds__(256) void k_gemm(
    const ushort* __restrict__ Hs, const ushort* __restrict__ Ag,
    const ushort* __restrict__ Wt, const float* __restrict__ bias,
    ushort* __restrict__ Hout, int M) {
    gemm_body<64, 128, 8, true, true, false>(blockIdx.x, threadIdx.x,
        Hs, Ag, Wt, 256, bias, Hout, M, 1, nullptr, nullptr, nullptr, nullptr);
}

// L1+d7: fused K=256 GEMM (Hb in LDS) + out_self/G2 epilogue
__global__ __launch_bounds__(256) void k_gemm1d7(
    const ushort* __restrict__ Hs, const ushort* __restrict__ Ag,
    const ushort* __restrict__ Wt, const float* __restrict__ bias,
    const ushort* __restrict__ Wt2, const float* __restrict__ b2,
    ushort* __restrict__ G2, float* __restrict__ out, int M) {
    gemm_body<64, 128, 8, true, true, true>(blockIdx.x, threadIdx.x,
        Hs, Ag, Wt, 256, bias, nullptr, M, 1, Wt2, b2, G2, out);
}

// ---------------- launch ----------------

static inline size_t align_up(size_t x) { return (x + 255) & ~(size_t)255; }

extern "C" void kernel_launch(void* const* d_in, const int* in_sizes, int n_in,
                              void* d_out, int out_size, void* d_ws, size_t ws_size,
                              hipStream_t stream) {
    const float* x   = (const float*)d_in[0];
    const int*   src = (const int*)d_in[1];
    const int*   dst = (const int*)d_in[2];
    const float* Ws0 = (const float*)d_in[3];
    const float* Wn0 = (const float*)d_in[4];
    const float* b0  = (const float*)d_in[5];
    const float* Ws1 = (const float*)d_in[6];
    const float* Wn1 = (const float*)d_in[7];
    const float* b1  = (const float*)d_in[8];
    const float* Ws2 = (const float*)d_in[9];
    const float* Wn2 = (const float*)d_in[10];
    const float* b2  = (const float*)d_in[11];
    float* out = (float*)d_out;

    const int NN = in_sizes[0] / NFEAT;   // 50000
    const int E  = in_sizes[1];           // 800000

    char* w = (char*)d_ws;
    ushort* X16  = (ushort*)w; w += align_up((size_t)NN * NFEAT * 2);
    ushort* Ha   = (ushort*)w; w += align_up((size_t)NN * NFEAT * 2);
    ushort* Hb   = (ushort*)w; w += align_up((size_t)NN * NFEAT * 2);   // scratch only
    ushort* AGG  = (ushort*)w; w += align_up((size_t)NN * NFEAT * 2);
    ushort* Wt0  = (ushort*)w; w += align_up((size_t)128 * 256 * 2);
    ushort* Wt1  = (ushort*)w; w += align_up((size_t)128 * 256 * 2);
    ushort* Wt2  = (ushort*)w; w += align_up((size_t)64 * 256 * 2);
    int* deg     = (int*)w;    w += align_up((size_t)NN * 4);
    ushort* csr  = (ushort*)w; w += align_up((size_t)NN * SLOTS * 2);   // 6.4 MB slot bins

    // edge-block geometry (tb=196 for E=800K)
    int epb = 4096;
    int tb = (E + epb - 1) / epb;
    if (tb > MAXTB) { epb = ((E + MAXTB - 1) / MAXTB + 1023) & ~(size_t)1023; tb = (E + epb - 1) / epb; }
    const int nbk = (NN + BNODES - 1) >> BSH;                           // 98

    // aliased scratch (lifetimes disjoint — all consumed by P2; later writers run after):
    unsigned* gbuf   = (unsigned*)Ha;     // nbk*tb*64*4 = 4.9 MB (Ha written by gemm0, after P2)
    int* lcnt_g      = (int*)Hb;          // nbk*tb*4 = 77 KB
    int* spill_cnt   = lcnt_g + nbk * tb; // 4 B
    unsigned* spill  = (unsigned*)AGG;    // up to E*4 = 3.2 MB (AGG written by agg0, after P2)
    ushort* G2       = X16;               // layer-2 projected table (X16 dead after gemm0)

    hipMemsetAsync(spill_cnt, 0, 4, stream);

    const int n2   = NN * NFEAT / 2;
    const int cvtb = (n2 + 255) / 256;        // 782
    const int wb   = (81920 + 255) / 256;     // 320
    const int gm   = (NN + 63) / 64;          // 782 (BM=64)
    const int agb  = 2048;

    // P1: bucket-scatter + cvt + weight prep
    k_p1<<<tb + cvtb + wb, 256, 0, stream>>>(
        dst, src, gbuf, lcnt_g, spill, spill_cnt, E, nbk, tb, epb,
        x, X16, n2,
        Ws0, Wn0, Ws1, Wn1, Ws2, Wn2, Wt0, Wt1, Wt2, cvtb);

    // P2: per-bucket binning (LDS atomics only)
    k_p2<<<nbk, 256, 0, stream>>>(
        gbuf, lcnt_g, spill, spill_cnt, deg, csr, NN, nbk, tb);

    // layer 0: X16 -> Ha (ReLU)
    k_agg128<<<agb, 256, 0, stream>>>(X16, deg, csr, AGG, NN);
    k_gemm<<<gm, 256, 0, stream>>>(X16, AGG, Wt0, b0, Ha, NN);

    // layer 1 + d7 fused: agg1 -> AGG; gemm1d7: Hb in LDS -> out_self + G2
    k_agg128<<<agb, 256, 0, stream>>>(Ha, deg, csr, AGG, NN);
    k_gemm1d7<<<gm, 256, 0, stream>>>(Ha, AGG, Wt1, b1, Wt2, b2, G2, out, NN);

    // final: out += mean-gather(G2)
    k_aggacc<<<agb, 256, 0, stream>>>(G2, deg, csr, out, NN);
}